// Round 1
// baseline (445.497 us; speedup 1.0000x reference)
//
#include <hip/hip_runtime.h>
#include <math.h>

#define DEVI __device__ __forceinline__

static constexpr float KD[10] = {
  0.027333068345077982f,  0.029519490925774643f, -0.039134249302383094f,
  0.1993975339773936f,    0.7234076904024206f,    0.6339789634582119f,
  0.01660210576452232f,  -0.17532808990845047f,  -0.021101834024758855f,
  0.019538882735286728f};

// IDWT stage: out[o] = sum_{s=0..4} K[2s + (o even ? 1 : 0)] * c[o/2 + s]
// (derived from conv_general_dilated with lhs_dilation=2, pad (1,1), taps=10;
//  output length 2n-8 is boundary-free: max index = n-1 exactly)

// waverec3 on a 20-vector, then accumulate smooth_l1(out[j] + off) over 100 outputs.
DEVI float recon_sl1(const float* c, float off) {
  float a1[31];
#pragma unroll
  for (int o = 0; o < 31; ++o) {
    int b = o >> 1;
    if (o & 1)
      a1[o] = KD[0]*c[b] + KD[2]*c[b+1] + KD[4]*c[b+2] + KD[6]*c[b+3] + KD[8]*c[b+4];
    else
      a1[o] = KD[1]*c[b] + KD[3]*c[b+1] + KD[5]*c[b+2] + KD[7]*c[b+3] + KD[9]*c[b+4];
  }
  float a2[54];
#pragma unroll
  for (int o = 0; o < 54; ++o) {
    int b = o >> 1;
    if (o & 1)
      a2[o] = KD[0]*a1[b] + KD[2]*a1[b+1] + KD[4]*a1[b+2] + KD[6]*a1[b+3] + KD[8]*a1[b+4];
    else
      a2[o] = KD[1]*a1[b] + KD[3]*a1[b+1] + KD[5]*a1[b+2] + KD[7]*a1[b+3] + KD[9]*a1[b+4];
  }
  float acc = 0.f;
#pragma unroll
  for (int o = 0; o < 100; ++o) {
    int b = o >> 1;
    float v;
    if (o & 1)
      v = KD[0]*a2[b] + KD[2]*a2[b+1] + KD[4]*a2[b+2] + KD[6]*a2[b+3] + KD[8]*a2[b+4];
    else
      v = KD[1]*a2[b] + KD[3]*a2[b+1] + KD[5]*a2[b+2] + KD[7]*a2[b+3] + KD[9]*a2[b+4];
    v += off;
    float a = fabsf(v);
    acc += (a < 1.f) ? 0.5f * v * v : a - 0.5f;
  }
  return acc;
}

DEVI float wave_sum(float v) {
#pragma unroll
  for (int d = 32; d; d >>= 1) v += __shfl_down(v, d);
  return v;
}

// acc layout (floats): [0]=cnt_pos [1]=cnt_neg [2]=sum_ce_pos
//                      [3]=sum_tcl_ttm [4]=sum_tcl_negm [5]=sum_ttm_perpix
__global__ void pixel_kernel(const float* __restrict__ cls, const float* __restrict__ reg,
                             const float* __restrict__ gt, float* __restrict__ ceArr,
                             float* __restrict__ acc, int M, int HW) {
  int p = blockIdx.x * blockDim.x + threadIdx.x;
  float cnt_pos = 0.f, cnt_neg = 0.f, s_ce_pos = 0.f, s_tcl_ttm = 0.f, s_tcl_negm = 0.f, s_ttm_pp = 0.f;
  if (p < M) {
    int n = p / HW, hw = p % HW;
    const float* cb = cls + (size_t)n * 4 * HW + hw;
    const float* gb = gt  + (size_t)n * 45 * HW + hw;
    const float* rb = reg + (size_t)n * 42 * HW + hw;
    float l0 = cb[0], l1 = cb[(size_t)HW], l2 = cb[2*(size_t)HW], l3 = cb[3*(size_t)HW];
    float tr = gb[0], tcl = gb[(size_t)HW], train = gb[2*(size_t)HW];

    float m1 = fmaxf(l0, l1);
    float lse1 = m1 + logf(expf(l0 - m1) + expf(l1 - m1));
    float ce_tr = lse1 - ((tr > 0.5f) ? l1 : l0);
    float m2 = fmaxf(l2, l3);
    float lse2 = m2 + logf(expf(l2 - m2) + expf(l3 - m2));
    float ce_tcl = lse2 - ((tcl > 0.5f) ? l3 : l2);

    float ttm = tr * train;
    bool pos = (tr * train) > 0.f;
    bool neg = ((1.f - tr) * train) > 0.f;
    ceArr[p] = neg ? ce_tr : 0.f;

    cnt_pos = pos ? 1.f : 0.f;
    cnt_neg = neg ? 1.f : 0.f;
    s_ce_pos = pos ? ce_tr : 0.f;
    s_tcl_ttm = ce_tcl * ttm;
    s_tcl_negm = ce_tcl * (1.f - ttm);

    // contour: linearity => reconstruct the difference once per axis
    float d[20];
#pragma unroll
    for (int c = 0; c < 20; ++c) d[c] = rb[(size_t)c * HW] - gb[(size_t)(3 + c) * HW];
    float dxc = rb[(size_t)20 * HW] - gb[(size_t)23 * HW];
    float pp = recon_sl1(d, dxc);
#pragma unroll
    for (int c = 0; c < 20; ++c) d[c] = rb[(size_t)(21 + c) * HW] - gb[(size_t)(24 + c) * HW];
    float dyc = rb[(size_t)41 * HW] - gb[(size_t)44 * HW];
    pp += recon_sl1(d, dyc);
    s_ttm_pp = ttm * pp;
  }
  int lane = threadIdx.x & 63;
  cnt_pos = wave_sum(cnt_pos);
  cnt_neg = wave_sum(cnt_neg);
  s_ce_pos = wave_sum(s_ce_pos);
  s_tcl_ttm = wave_sum(s_tcl_ttm);
  s_tcl_negm = wave_sum(s_tcl_negm);
  s_ttm_pp = wave_sum(s_ttm_pp);
  if (lane == 0) {
    atomicAdd(&acc[0], cnt_pos);
    atomicAdd(&acc[1], cnt_neg);
    atomicAdd(&acc[2], s_ce_pos);
    atomicAdd(&acc[3], s_tcl_ttm);
    atomicAdd(&acc[4], s_tcl_negm);
    atomicAdd(&acc[5], s_ttm_pp);
  }
}

DEVI float block_sum(float v, float* sh) {
  int lane = threadIdx.x & 63, wid = threadIdx.x >> 6;
  v = wave_sum(v);
  if (lane == 0) sh[wid] = v;
  __syncthreads();
  if (threadIdx.x == 0) {
    float s = 0.f;
    int nw = blockDim.x >> 6;
    for (int w = 0; w < nw; ++w) s += sh[w];
    sh[0] = s;
  }
  __syncthreads();
  float r = sh[0];
  __syncthreads();
  return r;
}

// one block per scale: radix-select top-k sum + final loss assembly
__global__ void finalize_kernel(const float* __restrict__ ws_ce, const float* __restrict__ ws_acc,
                                float* __restrict__ out) {
  int s = blockIdx.x;
  int M = (s == 0) ? 80000 : (s == 1 ? 20000 : 5000);
  int off = (s == 0) ? 0 : (s == 1 ? 80000 : 100000);
  const float* ceArr = ws_ce + off;
  const unsigned* bitsArr = (const unsigned*)ceArr;
  const float* acc = ws_acc + s * 8;

  __shared__ unsigned hist[256];
  __shared__ float sh_red[8];
  __shared__ unsigned sh_sel[2];

  float cnt_pos = acc[0];
  float cnt_neg_f = acc[1];
  float s_ce_pos = acc[2];
  float s_tcl_ttm = acc[3];
  float s_tcl_negm = acc[4];
  float s_ttm_pp = acc[5];
  int cnt_neg = (int)cnt_neg_f;

  // n_neg per reference: where(n_pos>0, min(count_neg, floor(3*n_pos)), 100)
  float kf = (cnt_pos > 0.f) ? fminf(cnt_neg_f, floorf(3.f * cnt_pos)) : 100.f;
  int k_take = min((int)kf, cnt_neg);

  int tid = threadIdx.x, nth = blockDim.x;
  float loss_neg = 0.f;

  if (k_take >= cnt_neg) {
    // take all negatives (non-neg slots hold 0.0f)
    float sum = 0.f;
    for (int i = tid; i < M; i += nth) sum += ceArr[i];
    loss_neg = block_sum(sum, sh_red);
  } else if (k_take > 0) {
    // radix select k-th largest (values are >= 0 => uint order == float order)
    unsigned prefix = 0;
    int remaining = k_take;
    for (int shift = 24; shift >= 0; shift -= 8) {
      for (int i = tid; i < 256; i += nth) hist[i] = 0u;
      __syncthreads();
      for (int i = tid; i < M; i += nth) {
        unsigned v = bitsArr[i];
        bool match = (shift == 24) || (((v ^ prefix) >> (shift + 8)) == 0u);
        if (match) atomicAdd(&hist[(v >> shift) & 255u], 1u);
      }
      __syncthreads();
      if (tid == 0) {
        int rem = remaining;
        unsigned chosen = 0u;
        for (int b = 255; b >= 0; --b) {
          unsigned h = hist[b];
          if ((unsigned)rem <= h) { chosen = (unsigned)b; break; }
          rem -= (int)h;
        }
        sh_sel[0] = chosen;
        sh_sel[1] = (unsigned)rem;
      }
      __syncthreads();
      prefix |= sh_sel[0] << shift;
      remaining = (int)sh_sel[1];
      __syncthreads();
    }
    float sum = 0.f, cgt = 0.f;
    for (int i = tid; i < M; i += nth) {
      unsigned v = bitsArr[i];
      if (v > prefix) { sum += ceArr[i]; cgt += 1.f; }
    }
    sum = block_sum(sum, sh_red);
    cgt = block_sum(cgt, sh_red);
    float vk = __uint_as_float(prefix);
    loss_neg = sum + ((float)k_take - cgt) * vk;
  }

  if (tid == 0) {
    float n_pos = cnt_pos;
    float loss_pos = (n_pos > 0.f) ? s_ce_pos : 0.f;
    float loss_tr = (loss_pos + loss_neg) / (n_pos + kf);

    float negm = (float)M - n_pos;  // sum(1 - ttm); ttm is 0/1
    float mp = s_tcl_ttm / fmaxf(n_pos, 1.f);
    float mn = s_tcl_negm / fmaxf(negm, 1.f);
    float loss_tcl = (n_pos > 0.f) ? (mp + 0.5f * mn) : 0.f;

    float loss_ct = (n_pos > 0.f) ? (0.5f * s_ttm_pp / (n_pos * 200.f)) : 0.f;

    atomicAdd(&out[0], loss_tr);
    atomicAdd(&out[1], loss_tcl);
    atomicAdd(&out[2], loss_ct);
  }
}

extern "C" void kernel_launch(void* const* d_in, const int* in_sizes, int n_in,
                              void* d_out, int out_size, void* d_ws, size_t ws_size,
                              hipStream_t stream) {
  (void)in_sizes; (void)n_in; (void)out_size; (void)ws_size;
  const float* cls3 = (const float*)d_in[0];
  const float* reg3 = (const float*)d_in[1];
  const float* gt3  = (const float*)d_in[2];
  const float* cls4 = (const float*)d_in[3];
  const float* reg4 = (const float*)d_in[4];
  const float* gt4  = (const float*)d_in[5];
  const float* cls5 = (const float*)d_in[6];
  const float* reg5 = (const float*)d_in[7];
  const float* gt5  = (const float*)d_in[8];

  float* ws = (float*)d_ws;
  float* out = (float*)d_out;
  float* ws_acc = ws + 105000;  // 3 scales x 8 floats

  hipMemsetAsync(d_out, 0, 3 * sizeof(float), stream);
  hipMemsetAsync(ws_acc, 0, 3 * 8 * sizeof(float), stream);

  pixel_kernel<<<(80000 + 255) / 256, 256, 0, stream>>>(cls3, reg3, gt3, ws + 0,      ws_acc + 0,  80000, 10000);
  pixel_kernel<<<(20000 + 255) / 256, 256, 0, stream>>>(cls4, reg4, gt4, ws + 80000,  ws_acc + 8,  20000, 2500);
  pixel_kernel<<<( 5000 + 255) / 256, 256, 0, stream>>>(cls5, reg5, gt5, ws + 100000, ws_acc + 16,  5000, 625);
  finalize_kernel<<<3, 256, 0, stream>>>(ws, ws_acc, out);
}

// Round 2
// 228.407 us; speedup vs baseline: 1.9505x; 1.9505x over previous
//
#include <hip/hip_runtime.h>
#include <math.h>

#define DEVI __device__ __forceinline__

static constexpr float KD[10] = {
  0.027333068345077982f,  0.029519490925774643f, -0.039134249302383094f,
  0.1993975339773936f,    0.7234076904024206f,    0.6339789634582119f,
  0.01660210576452232f,  -0.17532808990845047f,  -0.021101834024758855f,
  0.019538882735286728f};

// ---------- workspace layout (float offsets) ----------
#define CE_OFF     0         // 105000 floats (ce per pixel, 0 for non-negatives)
#define ACC_OFF    105000    // 3 x 8 floats
#define SUMGT_OFF  105024    // 3 floats (sum of ce strictly above chosen bin)
#define CCNT_OFF   105027    // 3 uints (compact counts)
#define STATE_OFF  105030    // 3 x 8 words: [0]=ibin [1]=rem [2]=kf(float) [3]=k_take
#define HIST_OFF   105054    // 3 x 65536 uints
#define CBUF_OFF   301662    // 3 x CAP floats
#define CAP        8192

// IDWT stage: out[o] = sum_{s=0..4} K[2s + (o even ? 1 : 0)] * c[o/2 + s]
// boundary-free (out length 2n-8, max index n-1)
DEVI float recon_sl1(const float* c, float off) {
  float a1[31];
#pragma unroll
  for (int o = 0; o < 31; ++o) {
    int b = o >> 1;
    if (o & 1)
      a1[o] = KD[0]*c[b] + KD[2]*c[b+1] + KD[4]*c[b+2] + KD[6]*c[b+3] + KD[8]*c[b+4];
    else
      a1[o] = KD[1]*c[b] + KD[3]*c[b+1] + KD[5]*c[b+2] + KD[7]*c[b+3] + KD[9]*c[b+4];
  }
  float a2[54];
#pragma unroll
  for (int o = 0; o < 54; ++o) {
    int b = o >> 1;
    if (o & 1)
      a2[o] = KD[0]*a1[b] + KD[2]*a1[b+1] + KD[4]*a1[b+2] + KD[6]*a1[b+3] + KD[8]*a1[b+4];
    else
      a2[o] = KD[1]*a1[b] + KD[3]*a1[b+1] + KD[5]*a1[b+2] + KD[7]*a1[b+3] + KD[9]*a1[b+4];
  }
  float acc = 0.f;
#pragma unroll
  for (int o = 0; o < 100; ++o) {
    int b = o >> 1;
    float v;
    if (o & 1)
      v = KD[0]*a2[b] + KD[2]*a2[b+1] + KD[4]*a2[b+2] + KD[6]*a2[b+3] + KD[8]*a2[b+4];
    else
      v = KD[1]*a2[b] + KD[3]*a2[b+1] + KD[5]*a2[b+2] + KD[7]*a2[b+3] + KD[9]*a2[b+4];
    v += off;
    float a = fabsf(v);
    acc += (a < 1.f) ? 0.5f * v * v : a - 0.5f;
  }
  return acc;
}

DEVI float wave_sum(float v) {
#pragma unroll
  for (int d = 32; d; d >>= 1) v += __shfl_down(v, d);
  return v;
}

DEVI float block_sum(float v, float* sh) {
  int lane = threadIdx.x & 63, wid = threadIdx.x >> 6;
  v = wave_sum(v);
  if (lane == 0) sh[wid] = v;
  __syncthreads();
  if (threadIdx.x == 0) {
    float s = 0.f;
    int nw = blockDim.x >> 6;
    for (int w = 0; w < nw; ++w) s += sh[w];
    sh[0] = s;
  }
  __syncthreads();
  float r = sh[0];
  __syncthreads();
  return r;
}

// inclusive suffix sum across 256 threads; sh must be int[256]
DEVI int suffix_scan_256(int v, int* sh) {
  int t = threadIdx.x;
  sh[t] = v;
  __syncthreads();
#pragma unroll
  for (int off = 1; off < 256; off <<= 1) {
    int x = (t + off < 256) ? sh[t + off] : 0;
    __syncthreads();
    sh[t] += x;
    __syncthreads();
  }
  return sh[t];
}

// acc: [0]=cnt_pos [1]=cnt_neg [2]=sum_ce_pos [3]=sum_tcl_ttm [4]=sum_tcl_negm [5]=sum_ttm_perpix
__global__ void pixel_kernel(const float* __restrict__ cls, const float* __restrict__ reg,
                             const float* __restrict__ gt, float* __restrict__ ceArr,
                             float* __restrict__ acc, unsigned* __restrict__ hist,
                             int M, int HW) {
  int p = blockIdx.x * blockDim.x + threadIdx.x;
  float cnt_pos = 0.f, cnt_neg = 0.f, s_ce_pos = 0.f, s_tcl_ttm = 0.f, s_tcl_negm = 0.f, s_ttm_pp = 0.f;
  if (p < M) {
    int n = p / HW, hw = p % HW;
    const float* cb = cls + (size_t)n * 4 * HW + hw;
    const float* gb = gt  + (size_t)n * 45 * HW + hw;
    const float* rb = reg + (size_t)n * 42 * HW + hw;
    float l0 = cb[0], l1 = cb[(size_t)HW], l2 = cb[2*(size_t)HW], l3 = cb[3*(size_t)HW];
    float tr = gb[0], tcl = gb[(size_t)HW], train = gb[2*(size_t)HW];

    float m1 = fmaxf(l0, l1);
    float lse1 = m1 + logf(expf(l0 - m1) + expf(l1 - m1));
    float ce_tr = lse1 - ((tr > 0.5f) ? l1 : l0);
    float m2 = fmaxf(l2, l3);
    float lse2 = m2 + logf(expf(l2 - m2) + expf(l3 - m2));
    float ce_tcl = lse2 - ((tcl > 0.5f) ? l3 : l2);

    float ttm = tr * train;
    bool pos = ttm > 0.f;
    bool neg = ((1.f - tr) * train) > 0.f;
    float cev = neg ? ce_tr : 0.f;
    ceArr[p] = cev;
    if (neg) atomicAdd(&hist[__float_as_uint(cev) >> 16], 1u);

    cnt_pos = pos ? 1.f : 0.f;
    cnt_neg = neg ? 1.f : 0.f;
    s_ce_pos = pos ? ce_tr : 0.f;
    s_tcl_ttm = ce_tcl * ttm;
    s_tcl_negm = ce_tcl * (1.f - ttm);

    float d[20];
#pragma unroll
    for (int c = 0; c < 20; ++c) d[c] = rb[(size_t)c * HW] - gb[(size_t)(3 + c) * HW];
    float dxc = rb[(size_t)20 * HW] - gb[(size_t)23 * HW];
    float pp = recon_sl1(d, dxc);
#pragma unroll
    for (int c = 0; c < 20; ++c) d[c] = rb[(size_t)(21 + c) * HW] - gb[(size_t)(24 + c) * HW];
    float dyc = rb[(size_t)41 * HW] - gb[(size_t)44 * HW];
    pp += recon_sl1(d, dyc);
    s_ttm_pp = ttm * pp;
  }
  int lane = threadIdx.x & 63;
  cnt_pos = wave_sum(cnt_pos);
  cnt_neg = wave_sum(cnt_neg);
  s_ce_pos = wave_sum(s_ce_pos);
  s_tcl_ttm = wave_sum(s_tcl_ttm);
  s_tcl_negm = wave_sum(s_tcl_negm);
  s_ttm_pp = wave_sum(s_ttm_pp);
  if (lane == 0) {
    atomicAdd(&acc[0], cnt_pos);
    atomicAdd(&acc[1], cnt_neg);
    atomicAdd(&acc[2], s_ce_pos);
    atomicAdd(&acc[3], s_tcl_ttm);
    atomicAdd(&acc[4], s_tcl_negm);
    atomicAdd(&acc[5], s_ttm_pp);
  }
}

// one block per scale: find the 16-bit bin holding the k-th largest negative CE
__global__ void select_bin_kernel(float* __restrict__ ws) {
  int s = blockIdx.x, t = threadIdx.x;
  const float* acc = ws + ACC_OFF + s * 8;
  int* st = (int*)(ws + STATE_OFF) + s * 8;
  const unsigned* hist = (const unsigned*)(ws + HIST_OFF) + s * 65536;

  __shared__ int sh[256];
  __shared__ int sel[2];

  float cnt_pos = acc[0], cnt_negf = acc[1];
  int cnt_neg = (int)cnt_negf;
  float kf = (cnt_pos > 0.f) ? fminf(cnt_negf, floorf(3.f * cnt_pos)) : 100.f;
  int k_take = min((int)kf, cnt_neg);

  int ibin, rem;
  if (k_take >= cnt_neg) { ibin = -1; rem = 0; }          // take all negatives
  else if (k_take <= 0)  { ibin = 65536; rem = 0; }       // take none
  else {
    // level 1: 256 chunk sums (each thread owns 256 contiguous bins)
    int psum = 0;
    const uint4* h4 = (const uint4*)(hist + t * 256);
#pragma unroll 8
    for (int j = 0; j < 64; ++j) { uint4 u = h4[j]; psum += (int)(u.x + u.y + u.z + u.w); }
    int suf = suffix_scan_256(psum, sh);
    int above = suf - psum;
    if (suf >= k_take && above < k_take) { sel[0] = t; sel[1] = k_take - above; }
    __syncthreads();
    int chunk = sel[0], remc = sel[1];
    __syncthreads();
    // level 2: bins within chunk (coalesced)
    int h = (int)hist[chunk * 256 + t];
    suf = suffix_scan_256(h, sh);
    above = suf - h;
    if (suf >= remc && above < remc) { sel[0] = chunk * 256 + t; sel[1] = remc - above; }
    __syncthreads();
    ibin = sel[0]; rem = sel[1];
  }
  if (t == 0) {
    st[0] = ibin;
    st[1] = rem;
    ((float*)st)[2] = kf;
    st[3] = k_take;
  }
}

// grid-wide: sum ce strictly above bin; compact in-bin values
__global__ void compact_kernel(float* __restrict__ ws) {
  int s = blockIdx.y;
  int M   = (s == 0) ? 80000 : (s == 1 ? 20000 : 5000);
  int off = (s == 0) ? 0     : (s == 1 ? 80000 : 100000);
  const int* st = (const int*)(ws + STATE_OFF) + s * 8;
  int ibin = st[0];
  float sum = 0.f;
  if (ibin < 65536) {
    const float* ce = ws + off;
    unsigned* ccnt = (unsigned*)(ws + CCNT_OFF) + s;
    float* cbuf = ws + CBUF_OFF + s * CAP;
    for (int i = blockIdx.x * blockDim.x + threadIdx.x; i < M; i += gridDim.x * blockDim.x) {
      float v = ce[i];
      int bin = (int)(__float_as_uint(v) >> 16);
      if (bin > ibin) sum += v;
      else if (bin == ibin) {
        unsigned idx = atomicAdd(ccnt, 1u);
        if (idx < CAP) cbuf[idx] = v;
      }
    }
  }
  sum = wave_sum(sum);
  if ((threadIdx.x & 63) == 0 && sum != 0.f) atomicAdd(ws + SUMGT_OFF + s, sum);
}

// one block per scale: exact k-th value within the bin (two 8-bit LDS radix passes), assemble losses
__global__ void final_kernel(float* __restrict__ ws, float* __restrict__ out) {
  int s = blockIdx.x, t = threadIdx.x;
  int M = (s == 0) ? 80000 : (s == 1 ? 20000 : 5000);
  const float* acc = ws + ACC_OFF + s * 8;
  const int* st = (const int*)(ws + STATE_OFF) + s * 8;

  __shared__ int hist[256];
  __shared__ int sh[256];
  __shared__ int sel[2];
  __shared__ float red[8];

  float cnt_pos = acc[0];
  float s_ce_pos = acc[2], s_tcl_ttm = acc[3], s_tcl_negm = acc[4], s_ttm_pp = acc[5];
  int ibin = st[0], rem = st[1];
  float kf = ((const float*)st)[2];
  float loss_neg = ws[SUMGT_OFF + s];

  if (rem > 0) {
    int cnt = min((int)((unsigned*)(ws + CCNT_OFF))[s], CAP);
    const float* cbuf = ws + CBUF_OFF + s * CAP;

    // pass 1: bits 15..8
    hist[t] = 0; __syncthreads();
    for (int i = t; i < cnt; i += 256)
      atomicAdd(&hist[(__float_as_uint(cbuf[i]) >> 8) & 255u], 1);
    __syncthreads();
    int h = hist[t];
    int suf = suffix_scan_256(h, sh);
    int above = suf - h;
    if (suf >= rem && above < rem) { sel[0] = t; sel[1] = rem - above; }
    __syncthreads();
    int b1 = sel[0], rem1 = sel[1];
    __syncthreads();

    // pass 2: bits 7..0
    hist[t] = 0; __syncthreads();
    for (int i = t; i < cnt; i += 256) {
      unsigned b = __float_as_uint(cbuf[i]);
      if (((b >> 8) & 255u) == (unsigned)b1) atomicAdd(&hist[b & 255u], 1);
    }
    __syncthreads();
    h = hist[t];
    suf = suffix_scan_256(h, sh);
    above = suf - h;
    if (suf >= rem1 && above < rem1) { sel[0] = t; }
    __syncthreads();
    int b0 = sel[0];
    __syncthreads();

    unsigned tbits = ((unsigned)ibin << 16) | ((unsigned)b1 << 8) | (unsigned)b0;
    float tval = __uint_as_float(tbits);

    float sum_in = 0.f, cgt = 0.f;
    for (int i = t; i < cnt; i += 256) {
      unsigned b = __float_as_uint(cbuf[i]);
      if (b > tbits) { sum_in += cbuf[i]; cgt += 1.f; }
    }
    sum_in = block_sum(sum_in, red);
    cgt = block_sum(cgt, red);
    loss_neg += sum_in + ((float)rem - cgt) * tval;
  }

  if (t == 0) {
    float n_pos = cnt_pos;
    float loss_pos = (n_pos > 0.f) ? s_ce_pos : 0.f;
    float loss_tr = (loss_pos + loss_neg) / (n_pos + kf);

    float negm = (float)M - n_pos;
    float mp = s_tcl_ttm / fmaxf(n_pos, 1.f);
    float mn = s_tcl_negm / fmaxf(negm, 1.f);
    float loss_tcl = (n_pos > 0.f) ? (mp + 0.5f * mn) : 0.f;

    float loss_ct = (n_pos > 0.f) ? (0.5f * s_ttm_pp / (n_pos * 200.f)) : 0.f;

    atomicAdd(&out[0], loss_tr);
    atomicAdd(&out[1], loss_tcl);
    atomicAdd(&out[2], loss_ct);
  }
}

extern "C" void kernel_launch(void* const* d_in, const int* in_sizes, int n_in,
                              void* d_out, int out_size, void* d_ws, size_t ws_size,
                              hipStream_t stream) {
  (void)in_sizes; (void)n_in; (void)out_size; (void)ws_size;
  const float* cls3 = (const float*)d_in[0];
  const float* reg3 = (const float*)d_in[1];
  const float* gt3  = (const float*)d_in[2];
  const float* cls4 = (const float*)d_in[3];
  const float* reg4 = (const float*)d_in[4];
  const float* gt4  = (const float*)d_in[5];
  const float* cls5 = (const float*)d_in[6];
  const float* reg5 = (const float*)d_in[7];
  const float* gt5  = (const float*)d_in[8];

  float* ws = (float*)d_ws;
  float* out = (float*)d_out;
  unsigned* hist = (unsigned*)(ws + HIST_OFF);

  hipMemsetAsync(d_out, 0, 3 * sizeof(float), stream);
  // zero acc + sumgt + ccnt + state + hist in one shot
  hipMemsetAsync(ws + ACC_OFF, 0, (size_t)(CBUF_OFF - ACC_OFF) * sizeof(float), stream);

  pixel_kernel<<<(80000 + 255) / 256, 256, 0, stream>>>(cls3, reg3, gt3, ws + 0,      ws + ACC_OFF + 0,  hist + 0 * 65536, 80000, 10000);
  pixel_kernel<<<(20000 + 255) / 256, 256, 0, stream>>>(cls4, reg4, gt4, ws + 80000,  ws + ACC_OFF + 8,  hist + 1 * 65536, 20000, 2500);
  pixel_kernel<<<( 5000 + 255) / 256, 256, 0, stream>>>(cls5, reg5, gt5, ws + 100000, ws + ACC_OFF + 16, hist + 2 * 65536,  5000, 625);

  select_bin_kernel<<<3, 256, 0, stream>>>(ws);
  compact_kernel<<<dim3(96, 3), 256, 0, stream>>>(ws);
  final_kernel<<<3, 256, 0, stream>>>(ws, out);
}

// Round 3
// 224.559 us; speedup vs baseline: 1.9839x; 1.0171x over previous
//
#include <hip/hip_runtime.h>
#include <math.h>

#define DEVI __device__ __forceinline__

static constexpr float KD[10] = {
  0.027333068345077982f,  0.029519490925774643f, -0.039134249302383094f,
  0.1993975339773936f,    0.7234076904024206f,    0.6339789634582119f,
  0.01660210576452232f,  -0.17532808990845047f,  -0.021101834024758855f,
  0.019538882735286728f};

// ---------- workspace layout (float offsets) ----------
#define CE_OFF     0         // 105000 floats (ce per pixel, 0 for non-negatives)
#define ACC_OFF    105000    // 3 x 8 floats
#define SUMGT_OFF  105024    // 3 floats (sum of ce strictly above chosen bin)
#define CCNT_OFF   105027    // 3 uints (compact counts)
#define STATE_OFF  105030    // 3 x 8 words: [0]=ibin [1]=rem [2]=kf(float) [3]=k_take
#define HIST_OFF   105054    // 3 x 65536 uints
#define CBUF_OFF   301662    // 3 x CAP floats
#define CAP        8192

// waverec3 on a 20-vector + offset, accumulating smooth_l1 over the 100 outputs.
// Stage 1 materializes a1[31]; stages 2+3 are fused with a 5-wide rolling
// window (a2[j] feeds outputs 2(j-4), 2(j-4)+1 exactly) -> peak live ~55 floats.
DEVI float recon_sl1(const float* c, float off) {
  float a1[31];
#pragma unroll
  for (int o = 0; o < 31; ++o) {
    int b = o >> 1;
    if (o & 1)
      a1[o] = KD[0]*c[b] + KD[2]*c[b+1] + KD[4]*c[b+2] + KD[6]*c[b+3] + KD[8]*c[b+4];
    else
      a1[o] = KD[1]*c[b] + KD[3]*c[b+1] + KD[5]*c[b+2] + KD[7]*c[b+3] + KD[9]*c[b+4];
  }
  float acc = 0.f;
  float w0 = 0.f, w1 = 0.f, w2 = 0.f, w3 = 0.f, w4 = 0.f;
#pragma unroll
  for (int j = 0; j < 54; ++j) {
    int b = j >> 1;
    float aj;
    if (j & 1)
      aj = KD[0]*a1[b] + KD[2]*a1[b+1] + KD[4]*a1[b+2] + KD[6]*a1[b+3] + KD[8]*a1[b+4];
    else
      aj = KD[1]*a1[b] + KD[3]*a1[b+1] + KD[5]*a1[b+2] + KD[7]*a1[b+3] + KD[9]*a1[b+4];
    w0 = w1; w1 = w2; w2 = w3; w3 = w4; w4 = aj;
    if (j >= 4) {
      float ve = KD[1]*w0 + KD[3]*w1 + KD[5]*w2 + KD[7]*w3 + KD[9]*w4 + off;
      float vo = KD[0]*w0 + KD[2]*w1 + KD[4]*w2 + KD[6]*w3 + KD[8]*w4 + off;
      float ae = fabsf(ve);
      acc += (ae < 1.f) ? 0.5f * ve * ve : ae - 0.5f;
      float ao = fabsf(vo);
      acc += (ao < 1.f) ? 0.5f * vo * vo : ao - 0.5f;
    }
  }
  return acc;
}

DEVI float wave_sum(float v) {
#pragma unroll
  for (int d = 32; d; d >>= 1) v += __shfl_down(v, d);
  return v;
}

DEVI float block_sum(float v, float* sh) {
  int lane = threadIdx.x & 63, wid = threadIdx.x >> 6;
  v = wave_sum(v);
  if (lane == 0) sh[wid] = v;
  __syncthreads();
  if (threadIdx.x == 0) {
    float s = 0.f;
    int nw = blockDim.x >> 6;
    for (int w = 0; w < nw; ++w) s += sh[w];
    sh[0] = s;
  }
  __syncthreads();
  float r = sh[0];
  __syncthreads();
  return r;
}

// inclusive suffix sum across 256 threads; sh must be int[256]
DEVI int suffix_scan_256(int v, int* sh) {
  int t = threadIdx.x;
  sh[t] = v;
  __syncthreads();
#pragma unroll
  for (int off = 1; off < 256; off <<= 1) {
    int x = (t + off < 256) ? sh[t + off] : 0;
    __syncthreads();
    sh[t] += x;
    __syncthreads();
  }
  return sh[t];
}

// acc: [0]=cnt_pos [1]=cnt_neg [2]=sum_ce_pos [3]=sum_tcl_ttm [4]=sum_tcl_negm [5]=sum_ttm_perpix
// blockIdx.y = axis (0: x-contour + all CE/mask work; 1: y-contour only)
__global__ void __launch_bounds__(256, 2)
pixel_kernel(const float* __restrict__ cls, const float* __restrict__ reg,
             const float* __restrict__ gt, float* __restrict__ ceArr,
             float* __restrict__ acc, unsigned* __restrict__ hist,
             int M, int HW) {
  int p = blockIdx.x * blockDim.x + threadIdx.x;
  int axis = blockIdx.y;
  float cnt_pos = 0.f, cnt_neg = 0.f, s_ce_pos = 0.f, s_tcl_ttm = 0.f, s_tcl_negm = 0.f;
  float s_ttm_pp = 0.f;
  if (p < M) {
    int n = p / HW, hw = p % HW;
    const float* gb = gt  + (size_t)n * 45 * HW + hw;
    const float* rb = reg + (size_t)n * 42 * HW + hw;
    float tr = gb[0], train = gb[2*(size_t)HW];
    float ttm = tr * train;

    if (axis == 0) {
      const float* cb = cls + (size_t)n * 4 * HW + hw;
      float l0 = cb[0], l1 = cb[(size_t)HW], l2 = cb[2*(size_t)HW], l3 = cb[3*(size_t)HW];
      float tcl = gb[(size_t)HW];

      float m1 = fmaxf(l0, l1);
      float lse1 = m1 + logf(expf(l0 - m1) + expf(l1 - m1));
      float ce_tr = lse1 - ((tr > 0.5f) ? l1 : l0);
      float m2 = fmaxf(l2, l3);
      float lse2 = m2 + logf(expf(l2 - m2) + expf(l3 - m2));
      float ce_tcl = lse2 - ((tcl > 0.5f) ? l3 : l2);

      bool pos = ttm > 0.f;
      bool neg = ((1.f - tr) * train) > 0.f;
      float cev = neg ? ce_tr : 0.f;
      ceArr[p] = cev;
      if (neg) atomicAdd(&hist[__float_as_uint(cev) >> 16], 1u);

      cnt_pos = pos ? 1.f : 0.f;
      cnt_neg = neg ? 1.f : 0.f;
      s_ce_pos = pos ? ce_tr : 0.f;
      s_tcl_ttm = ce_tcl * ttm;
      s_tcl_negm = ce_tcl * (1.f - ttm);
    }

    // contour (this axis): linearity => reconstruct the coefficient difference
    int rc0 = (axis == 0) ? 0 : 21;   // reg channels [rc0, rc0+20], center rc0+20
    int gc0 = (axis == 0) ? 3 : 24;   // gt channels  [gc0, gc0+20], center gc0+20
    float d[20];
#pragma unroll
    for (int c = 0; c < 20; ++c) d[c] = rb[(size_t)(rc0 + c) * HW] - gb[(size_t)(gc0 + c) * HW];
    float dc = rb[(size_t)(rc0 + 20) * HW] - gb[(size_t)(gc0 + 20) * HW];
    s_ttm_pp = ttm * recon_sl1(d, dc);
  }
  int lane = threadIdx.x & 63;
  s_ttm_pp = wave_sum(s_ttm_pp);
  if (axis == 0) {
    cnt_pos = wave_sum(cnt_pos);
    cnt_neg = wave_sum(cnt_neg);
    s_ce_pos = wave_sum(s_ce_pos);
    s_tcl_ttm = wave_sum(s_tcl_ttm);
    s_tcl_negm = wave_sum(s_tcl_negm);
    if (lane == 0) {
      atomicAdd(&acc[0], cnt_pos);
      atomicAdd(&acc[1], cnt_neg);
      atomicAdd(&acc[2], s_ce_pos);
      atomicAdd(&acc[3], s_tcl_ttm);
      atomicAdd(&acc[4], s_tcl_negm);
    }
  }
  if (lane == 0) atomicAdd(&acc[5], s_ttm_pp);
}

// one block per scale: find the 16-bit bin holding the k-th largest negative CE
__global__ void select_bin_kernel(float* __restrict__ ws) {
  int s = blockIdx.x, t = threadIdx.x;
  const float* acc = ws + ACC_OFF + s * 8;
  int* st = (int*)(ws + STATE_OFF) + s * 8;
  const unsigned* hist = (const unsigned*)(ws + HIST_OFF) + s * 65536;

  __shared__ int sh[256];
  __shared__ int sel[2];

  float cnt_pos = acc[0], cnt_negf = acc[1];
  int cnt_neg = (int)cnt_negf;
  float kf = (cnt_pos > 0.f) ? fminf(cnt_negf, floorf(3.f * cnt_pos)) : 100.f;
  int k_take = min((int)kf, cnt_neg);

  int ibin, rem;
  if (k_take >= cnt_neg) { ibin = -1; rem = 0; }          // take all negatives
  else if (k_take <= 0)  { ibin = 65536; rem = 0; }       // take none
  else {
    // level 1: 256 chunk sums (each thread owns 256 contiguous bins)
    int psum = 0;
    const uint4* h4 = (const uint4*)(hist + t * 256);
#pragma unroll 8
    for (int j = 0; j < 64; ++j) { uint4 u = h4[j]; psum += (int)(u.x + u.y + u.z + u.w); }
    int suf = suffix_scan_256(psum, sh);
    int above = suf - psum;
    if (suf >= k_take && above < k_take) { sel[0] = t; sel[1] = k_take - above; }
    __syncthreads();
    int chunk = sel[0], remc = sel[1];
    __syncthreads();
    // level 2: bins within chunk (coalesced)
    int h = (int)hist[chunk * 256 + t];
    suf = suffix_scan_256(h, sh);
    above = suf - h;
    if (suf >= remc && above < remc) { sel[0] = chunk * 256 + t; sel[1] = remc - above; }
    __syncthreads();
    ibin = sel[0]; rem = sel[1];
  }
  if (t == 0) {
    st[0] = ibin;
    st[1] = rem;
    ((float*)st)[2] = kf;
    st[3] = k_take;
  }
}

// grid-wide: sum ce strictly above bin; compact in-bin values
__global__ void compact_kernel(float* __restrict__ ws) {
  int s = blockIdx.y;
  int M   = (s == 0) ? 80000 : (s == 1 ? 20000 : 5000);
  int off = (s == 0) ? 0     : (s == 1 ? 80000 : 100000);
  const int* st = (const int*)(ws + STATE_OFF) + s * 8;
  int ibin = st[0];
  float sum = 0.f;
  if (ibin < 65536) {
    const float* ce = ws + off;
    unsigned* ccnt = (unsigned*)(ws + CCNT_OFF) + s;
    float* cbuf = ws + CBUF_OFF + s * CAP;
    for (int i = blockIdx.x * blockDim.x + threadIdx.x; i < M; i += gridDim.x * blockDim.x) {
      float v = ce[i];
      int bin = (int)(__float_as_uint(v) >> 16);
      if (bin > ibin) sum += v;
      else if (bin == ibin) {
        unsigned idx = atomicAdd(ccnt, 1u);
        if (idx < CAP) cbuf[idx] = v;
      }
    }
  }
  sum = wave_sum(sum);
  if ((threadIdx.x & 63) == 0 && sum != 0.f) atomicAdd(ws + SUMGT_OFF + s, sum);
}

// one block per scale: exact k-th value within the bin (two 8-bit LDS radix passes), assemble losses
__global__ void final_kernel(float* __restrict__ ws, float* __restrict__ out) {
  int s = blockIdx.x, t = threadIdx.x;
  int M = (s == 0) ? 80000 : (s == 1 ? 20000 : 5000);
  const float* acc = ws + ACC_OFF + s * 8;
  const int* st = (const int*)(ws + STATE_OFF) + s * 8;

  __shared__ int hist[256];
  __shared__ int sh[256];
  __shared__ int sel[2];
  __shared__ float red[8];

  float cnt_pos = acc[0];
  float s_ce_pos = acc[2], s_tcl_ttm = acc[3], s_tcl_negm = acc[4], s_ttm_pp = acc[5];
  int ibin = st[0], rem = st[1];
  float kf = ((const float*)st)[2];
  float loss_neg = ws[SUMGT_OFF + s];

  if (rem > 0) {
    int cnt = min((int)((unsigned*)(ws + CCNT_OFF))[s], CAP);
    const float* cbuf = ws + CBUF_OFF + s * CAP;

    // pass 1: bits 15..8
    hist[t] = 0; __syncthreads();
    for (int i = t; i < cnt; i += 256)
      atomicAdd(&hist[(__float_as_uint(cbuf[i]) >> 8) & 255u], 1);
    __syncthreads();
    int h = hist[t];
    int suf = suffix_scan_256(h, sh);
    int above = suf - h;
    if (suf >= rem && above < rem) { sel[0] = t; sel[1] = rem - above; }
    __syncthreads();
    int b1 = sel[0], rem1 = sel[1];
    __syncthreads();

    // pass 2: bits 7..0
    hist[t] = 0; __syncthreads();
    for (int i = t; i < cnt; i += 256) {
      unsigned b = __float_as_uint(cbuf[i]);
      if (((b >> 8) & 255u) == (unsigned)b1) atomicAdd(&hist[b & 255u], 1);
    }
    __syncthreads();
    h = hist[t];
    suf = suffix_scan_256(h, sh);
    above = suf - h;
    if (suf >= rem1 && above < rem1) { sel[0] = t; }
    __syncthreads();
    int b0 = sel[0];
    __syncthreads();

    unsigned tbits = ((unsigned)ibin << 16) | ((unsigned)b1 << 8) | (unsigned)b0;
    float tval = __uint_as_float(tbits);

    float sum_in = 0.f, cgt = 0.f;
    for (int i = t; i < cnt; i += 256) {
      unsigned b = __float_as_uint(cbuf[i]);
      if (b > tbits) { sum_in += cbuf[i]; cgt += 1.f; }
    }
    sum_in = block_sum(sum_in, red);
    cgt = block_sum(cgt, red);
    loss_neg += sum_in + ((float)rem - cgt) * tval;
  }

  if (t == 0) {
    float n_pos = cnt_pos;
    float loss_pos = (n_pos > 0.f) ? s_ce_pos : 0.f;
    float loss_tr = (loss_pos + loss_neg) / (n_pos + kf);

    float negm = (float)M - n_pos;
    float mp = s_tcl_ttm / fmaxf(n_pos, 1.f);
    float mn = s_tcl_negm / fmaxf(negm, 1.f);
    float loss_tcl = (n_pos > 0.f) ? (mp + 0.5f * mn) : 0.f;

    float loss_ct = (n_pos > 0.f) ? (0.5f * s_ttm_pp / (n_pos * 200.f)) : 0.f;

    atomicAdd(&out[0], loss_tr);
    atomicAdd(&out[1], loss_tcl);
    atomicAdd(&out[2], loss_ct);
  }
}

extern "C" void kernel_launch(void* const* d_in, const int* in_sizes, int n_in,
                              void* d_out, int out_size, void* d_ws, size_t ws_size,
                              hipStream_t stream) {
  (void)in_sizes; (void)n_in; (void)out_size; (void)ws_size;
  const float* cls3 = (const float*)d_in[0];
  const float* reg3 = (const float*)d_in[1];
  const float* gt3  = (const float*)d_in[2];
  const float* cls4 = (const float*)d_in[3];
  const float* reg4 = (const float*)d_in[4];
  const float* gt4  = (const float*)d_in[5];
  const float* cls5 = (const float*)d_in[6];
  const float* reg5 = (const float*)d_in[7];
  const float* gt5  = (const float*)d_in[8];

  float* ws = (float*)d_ws;
  float* out = (float*)d_out;
  unsigned* hist = (unsigned*)(ws + HIST_OFF);

  hipMemsetAsync(d_out, 0, 3 * sizeof(float), stream);
  // zero acc + sumgt + ccnt + state + hist in one shot
  hipMemsetAsync(ws + ACC_OFF, 0, (size_t)(CBUF_OFF - ACC_OFF) * sizeof(float), stream);

  pixel_kernel<<<dim3((80000 + 255) / 256, 2), 256, 0, stream>>>(cls3, reg3, gt3, ws + 0,      ws + ACC_OFF + 0,  hist + 0 * 65536, 80000, 10000);
  pixel_kernel<<<dim3((20000 + 255) / 256, 2), 256, 0, stream>>>(cls4, reg4, gt4, ws + 80000,  ws + ACC_OFF + 8,  hist + 1 * 65536, 20000, 2500);
  pixel_kernel<<<dim3(( 5000 + 255) / 256, 2), 256, 0, stream>>>(cls5, reg5, gt5, ws + 100000, ws + ACC_OFF + 16, hist + 2 * 65536,  5000, 625);

  select_bin_kernel<<<3, 256, 0, stream>>>(ws);
  compact_kernel<<<dim3(96, 3), 256, 0, stream>>>(ws);
  final_kernel<<<3, 256, 0, stream>>>(ws, out);
}

// Round 4
// 104.910 us; speedup vs baseline: 4.2465x; 2.1405x over previous
//
#include <hip/hip_runtime.h>
#include <math.h>

#define DEVI __device__ __forceinline__

static constexpr float KD[10] = {
  0.027333068345077982f,  0.029519490925774643f, -0.039134249302383094f,
  0.1993975339773936f,    0.7234076904024206f,    0.6339789634582119f,
  0.01660210576452232f,  -0.17532808990845047f,  -0.021101834024758855f,
  0.019538882735286728f};

// ---------- workspace layout (float offsets) ----------
#define CE_OFF     0         // 105000 floats (ce per pixel, 0 for non-negatives)
#define ACC_OFF    105000    // 3 x 8 floats  (written by select_bin after partial-reduce)
#define SUMGT_OFF  105024    // 3 floats (sum of ce strictly above chosen bin)
#define CCNT_OFF   105027    // 3 uints (compact counts)
#define STATE_OFF  105030    // 3 x 8 words: [0]=ibin [1]=rem [2]=kf(float) [3]=k_take
#define HIST_OFF   105054    // 3 x 65536 uints
#define CBUF_OFF   301662    // 3 x CAP floats
#define CAP        8192
#define PART_OFF   326238    // 3 x 626 x 6 floats (per-block partials, no atomics)
#define PART_STRIDE 3756     // 626*6

// waverec3 on a 20-vector + offset, accumulating smooth_l1 over the 100 outputs.
// Stage 1 materializes a1[31]; stages 2+3 fused with a 5-wide rolling window.
DEVI float recon_sl1(const float* c, float off) {
  float a1[31];
#pragma unroll
  for (int o = 0; o < 31; ++o) {
    int b = o >> 1;
    if (o & 1)
      a1[o] = KD[0]*c[b] + KD[2]*c[b+1] + KD[4]*c[b+2] + KD[6]*c[b+3] + KD[8]*c[b+4];
    else
      a1[o] = KD[1]*c[b] + KD[3]*c[b+1] + KD[5]*c[b+2] + KD[7]*c[b+3] + KD[9]*c[b+4];
  }
  float acc = 0.f;
  float w0 = 0.f, w1 = 0.f, w2 = 0.f, w3 = 0.f, w4 = 0.f;
#pragma unroll
  for (int j = 0; j < 54; ++j) {
    int b = j >> 1;
    float aj;
    if (j & 1)
      aj = KD[0]*a1[b] + KD[2]*a1[b+1] + KD[4]*a1[b+2] + KD[6]*a1[b+3] + KD[8]*a1[b+4];
    else
      aj = KD[1]*a1[b] + KD[3]*a1[b+1] + KD[5]*a1[b+2] + KD[7]*a1[b+3] + KD[9]*a1[b+4];
    w0 = w1; w1 = w2; w2 = w3; w3 = w4; w4 = aj;
    if (j >= 4) {
      float ve = KD[1]*w0 + KD[3]*w1 + KD[5]*w2 + KD[7]*w3 + KD[9]*w4 + off;
      float vo = KD[0]*w0 + KD[2]*w1 + KD[4]*w2 + KD[6]*w3 + KD[8]*w4 + off;
      float ae = fabsf(ve);
      acc += (ae < 1.f) ? 0.5f * ve * ve : ae - 0.5f;
      float ao = fabsf(vo);
      acc += (ao < 1.f) ? 0.5f * vo * vo : ao - 0.5f;
    }
  }
  return acc;
}

DEVI float wave_sum(float v) {
#pragma unroll
  for (int d = 32; d; d >>= 1) v += __shfl_down(v, d);
  return v;
}

DEVI float block_sum(float v, float* sh) {
  int lane = threadIdx.x & 63, wid = threadIdx.x >> 6;
  v = wave_sum(v);
  if (lane == 0) sh[wid] = v;
  __syncthreads();
  if (threadIdx.x == 0) {
    float s = 0.f;
    int nw = blockDim.x >> 6;
    for (int w = 0; w < nw; ++w) s += sh[w];
    sh[0] = s;
  }
  __syncthreads();
  float r = sh[0];
  __syncthreads();
  return r;
}

// inclusive suffix sum across 256 threads; sh must be int[256]
DEVI int suffix_scan_256(int v, int* sh) {
  int t = threadIdx.x;
  sh[t] = v;
  __syncthreads();
#pragma unroll
  for (int off = 1; off < 256; off <<= 1) {
    int x = (t + off < 256) ? sh[t + off] : 0;
    __syncthreads();
    sh[t] += x;
    __syncthreads();
  }
  return sh[t];
}

// partials per block slot: [0]=cnt_pos [1]=cnt_neg [2]=sum_ce_pos
//                          [3]=sum_tcl_ttm [4]=sum_tcl_negm [5]=sum_ttm_perpix
// blockIdx.y = axis (0: x-contour + all CE/mask work; 1: y-contour only)
__global__ void __launch_bounds__(256, 2)
pixel_kernel(const float* __restrict__ cls, const float* __restrict__ reg,
             const float* __restrict__ gt, float* __restrict__ ceArr,
             float* __restrict__ part, unsigned* __restrict__ hist,
             int M, int HW) {
  int p = blockIdx.x * blockDim.x + threadIdx.x;
  int axis = blockIdx.y;
  float cnt_pos = 0.f, cnt_neg = 0.f, s_ce_pos = 0.f, s_tcl_ttm = 0.f, s_tcl_negm = 0.f;
  float s_ttm_pp = 0.f;
  if (p < M) {
    int n = p / HW, hw = p % HW;
    const float* gb = gt  + (size_t)n * 45 * HW + hw;
    const float* rb = reg + (size_t)n * 42 * HW + hw;
    float tr = gb[0], train = gb[2*(size_t)HW];
    float ttm = tr * train;

    if (axis == 0) {
      const float* cb = cls + (size_t)n * 4 * HW + hw;
      float l0 = cb[0], l1 = cb[(size_t)HW], l2 = cb[2*(size_t)HW], l3 = cb[3*(size_t)HW];
      float tcl = gb[(size_t)HW];

      float m1 = fmaxf(l0, l1);
      float lse1 = m1 + logf(expf(l0 - m1) + expf(l1 - m1));
      float ce_tr = lse1 - ((tr > 0.5f) ? l1 : l0);
      float m2 = fmaxf(l2, l3);
      float lse2 = m2 + logf(expf(l2 - m2) + expf(l3 - m2));
      float ce_tcl = lse2 - ((tcl > 0.5f) ? l3 : l2);

      bool pos = ttm > 0.f;
      bool neg = ((1.f - tr) * train) > 0.f;
      float cev = neg ? ce_tr : 0.f;
      ceArr[p] = cev;
      if (neg) atomicAdd(&hist[__float_as_uint(cev) >> 16], 1u);

      cnt_pos = pos ? 1.f : 0.f;
      cnt_neg = neg ? 1.f : 0.f;
      s_ce_pos = pos ? ce_tr : 0.f;
      s_tcl_ttm = ce_tcl * ttm;
      s_tcl_negm = ce_tcl * (1.f - ttm);
    }

    // contour (this axis): linearity => reconstruct the coefficient difference
    int rc0 = (axis == 0) ? 0 : 21;
    int gc0 = (axis == 0) ? 3 : 24;
    float d[20];
#pragma unroll
    for (int c = 0; c < 20; ++c) d[c] = rb[(size_t)(rc0 + c) * HW] - gb[(size_t)(gc0 + c) * HW];
    float dc = rb[(size_t)(rc0 + 20) * HW] - gb[(size_t)(gc0 + 20) * HW];
    s_ttm_pp = ttm * recon_sl1(d, dc);
  }

  __shared__ float shp[4][6];
  int lane = threadIdx.x & 63, wid = threadIdx.x >> 6;
  cnt_pos = wave_sum(cnt_pos);
  cnt_neg = wave_sum(cnt_neg);
  s_ce_pos = wave_sum(s_ce_pos);
  s_tcl_ttm = wave_sum(s_tcl_ttm);
  s_tcl_negm = wave_sum(s_tcl_negm);
  s_ttm_pp = wave_sum(s_ttm_pp);
  if (lane == 0) {
    shp[wid][0] = cnt_pos; shp[wid][1] = cnt_neg; shp[wid][2] = s_ce_pos;
    shp[wid][3] = s_tcl_ttm; shp[wid][4] = s_tcl_negm; shp[wid][5] = s_ttm_pp;
  }
  __syncthreads();
  if (threadIdx.x < 6) {
    float s = shp[0][threadIdx.x] + shp[1][threadIdx.x] + shp[2][threadIdx.x] + shp[3][threadIdx.x];
    part[(size_t)(axis * gridDim.x + blockIdx.x) * 6 + threadIdx.x] = s;
  }
}

// one block per scale: reduce partials -> acc, then find the 16-bit bin
// holding the k-th largest negative CE
__global__ void select_bin_kernel(float* __restrict__ ws) {
  int s = blockIdx.x, t = threadIdx.x;
  float* acc = ws + ACC_OFF + s * 8;
  int* st = (int*)(ws + STATE_OFF) + s * 8;
  const unsigned* hist = (const unsigned*)(ws + HIST_OFF) + s * 65536;
  const float* part = ws + PART_OFF + s * PART_STRIDE;
  int npart = (s == 0) ? 626 : (s == 1 ? 158 : 40);

  __shared__ int sh[256];
  __shared__ int sel[2];
  __shared__ float red[4];

  // reduce per-block partials (deterministic order per thread, then block_sum)
  float a0 = 0.f, a1 = 0.f, a2 = 0.f, a3 = 0.f, a4 = 0.f, a5 = 0.f;
  for (int i = t; i < npart; i += 256) {
    const float* p6 = part + (size_t)i * 6;
    a0 += p6[0]; a1 += p6[1]; a2 += p6[2]; a3 += p6[3]; a4 += p6[4]; a5 += p6[5];
  }
  a0 = block_sum(a0, red);
  a1 = block_sum(a1, red);
  a2 = block_sum(a2, red);
  a3 = block_sum(a3, red);
  a4 = block_sum(a4, red);
  a5 = block_sum(a5, red);
  if (t == 0) { acc[0] = a0; acc[1] = a1; acc[2] = a2; acc[3] = a3; acc[4] = a4; acc[5] = a5; }

  float cnt_pos = a0, cnt_negf = a1;
  int cnt_neg = (int)cnt_negf;
  float kf = (cnt_pos > 0.f) ? fminf(cnt_negf, floorf(3.f * cnt_pos)) : 100.f;
  int k_take = min((int)kf, cnt_neg);

  int ibin, rem;
  if (k_take >= cnt_neg) { ibin = -1; rem = 0; }          // take all negatives
  else if (k_take <= 0)  { ibin = 65536; rem = 0; }       // take none
  else {
    // level 1: 256 chunk sums (each thread owns 256 contiguous bins)
    int psum = 0;
    const uint4* h4 = (const uint4*)(hist + t * 256);
#pragma unroll 8
    for (int j = 0; j < 64; ++j) { uint4 u = h4[j]; psum += (int)(u.x + u.y + u.z + u.w); }
    int suf = suffix_scan_256(psum, sh);
    int above = suf - psum;
    if (suf >= k_take && above < k_take) { sel[0] = t; sel[1] = k_take - above; }
    __syncthreads();
    int chunk = sel[0], remc = sel[1];
    __syncthreads();
    // level 2: bins within chunk (coalesced)
    int h = (int)hist[chunk * 256 + t];
    suf = suffix_scan_256(h, sh);
    above = suf - h;
    if (suf >= remc && above < remc) { sel[0] = chunk * 256 + t; sel[1] = remc - above; }
    __syncthreads();
    ibin = sel[0]; rem = sel[1];
  }
  if (t == 0) {
    st[0] = ibin;
    st[1] = rem;
    ((float*)st)[2] = kf;
    st[3] = k_take;
  }
}

// grid-wide: sum ce strictly above bin; compact in-bin values
__global__ void compact_kernel(float* __restrict__ ws) {
  int s = blockIdx.y;
  int M   = (s == 0) ? 80000 : (s == 1 ? 20000 : 5000);
  int off = (s == 0) ? 0     : (s == 1 ? 80000 : 100000);
  const int* st = (const int*)(ws + STATE_OFF) + s * 8;
  int ibin = st[0];
  float sum = 0.f;
  __shared__ float red[4];
  if (ibin < 65536) {
    const float* ce = ws + off;
    unsigned* ccnt = (unsigned*)(ws + CCNT_OFF) + s;
    float* cbuf = ws + CBUF_OFF + s * CAP;
    for (int i = blockIdx.x * blockDim.x + threadIdx.x; i < M; i += gridDim.x * blockDim.x) {
      float v = ce[i];
      int bin = (int)(__float_as_uint(v) >> 16);
      if (bin > ibin) sum += v;
      else if (bin == ibin) {
        unsigned idx = atomicAdd(ccnt, 1u);
        if (idx < CAP) cbuf[idx] = v;
      }
    }
  }
  sum = block_sum(sum, red);
  if (threadIdx.x == 0 && sum != 0.f) atomicAdd(ws + SUMGT_OFF + s, sum);
}

// one block per scale: exact k-th value within the bin (two 8-bit LDS radix passes), assemble losses
__global__ void final_kernel(float* __restrict__ ws, float* __restrict__ out) {
  int s = blockIdx.x, t = threadIdx.x;
  int M = (s == 0) ? 80000 : (s == 1 ? 20000 : 5000);
  const float* acc = ws + ACC_OFF + s * 8;
  const int* st = (const int*)(ws + STATE_OFF) + s * 8;

  __shared__ int hist[256];
  __shared__ int sh[256];
  __shared__ int sel[2];
  __shared__ float red[8];

  float cnt_pos = acc[0];
  float s_ce_pos = acc[2], s_tcl_ttm = acc[3], s_tcl_negm = acc[4], s_ttm_pp = acc[5];
  int ibin = st[0], rem = st[1];
  float kf = ((const float*)st)[2];
  float loss_neg = ws[SUMGT_OFF + s];

  if (rem > 0) {
    int cnt = min((int)((unsigned*)(ws + CCNT_OFF))[s], CAP);
    const float* cbuf = ws + CBUF_OFF + s * CAP;

    // pass 1: bits 15..8
    hist[t] = 0; __syncthreads();
    for (int i = t; i < cnt; i += 256)
      atomicAdd(&hist[(__float_as_uint(cbuf[i]) >> 8) & 255u], 1);
    __syncthreads();
    int h = hist[t];
    int suf = suffix_scan_256(h, sh);
    int above = suf - h;
    if (suf >= rem && above < rem) { sel[0] = t; sel[1] = rem - above; }
    __syncthreads();
    int b1 = sel[0], rem1 = sel[1];
    __syncthreads();

    // pass 2: bits 7..0
    hist[t] = 0; __syncthreads();
    for (int i = t; i < cnt; i += 256) {
      unsigned b = __float_as_uint(cbuf[i]);
      if (((b >> 8) & 255u) == (unsigned)b1) atomicAdd(&hist[b & 255u], 1);
    }
    __syncthreads();
    h = hist[t];
    suf = suffix_scan_256(h, sh);
    above = suf - h;
    if (suf >= rem1 && above < rem1) { sel[0] = t; }
    __syncthreads();
    int b0 = sel[0];
    __syncthreads();

    unsigned tbits = ((unsigned)ibin << 16) | ((unsigned)b1 << 8) | (unsigned)b0;
    float tval = __uint_as_float(tbits);

    float sum_in = 0.f, cgt = 0.f;
    for (int i = t; i < cnt; i += 256) {
      unsigned b = __float_as_uint(cbuf[i]);
      if (b > tbits) { sum_in += cbuf[i]; cgt += 1.f; }
    }
    sum_in = block_sum(sum_in, red);
    cgt = block_sum(cgt, red);
    loss_neg += sum_in + ((float)rem - cgt) * tval;
  }

  if (t == 0) {
    float n_pos = cnt_pos;
    float loss_pos = (n_pos > 0.f) ? s_ce_pos : 0.f;
    float loss_tr = (loss_pos + loss_neg) / (n_pos + kf);

    float negm = (float)M - n_pos;
    float mp = s_tcl_ttm / fmaxf(n_pos, 1.f);
    float mn = s_tcl_negm / fmaxf(negm, 1.f);
    float loss_tcl = (n_pos > 0.f) ? (mp + 0.5f * mn) : 0.f;

    float loss_ct = (n_pos > 0.f) ? (0.5f * s_ttm_pp / (n_pos * 200.f)) : 0.f;

    atomicAdd(&out[0], loss_tr);
    atomicAdd(&out[1], loss_tcl);
    atomicAdd(&out[2], loss_ct);
  }
}

extern "C" void kernel_launch(void* const* d_in, const int* in_sizes, int n_in,
                              void* d_out, int out_size, void* d_ws, size_t ws_size,
                              hipStream_t stream) {
  (void)in_sizes; (void)n_in; (void)out_size; (void)ws_size;
  const float* cls3 = (const float*)d_in[0];
  const float* reg3 = (const float*)d_in[1];
  const float* gt3  = (const float*)d_in[2];
  const float* cls4 = (const float*)d_in[3];
  const float* reg4 = (const float*)d_in[4];
  const float* gt4  = (const float*)d_in[5];
  const float* cls5 = (const float*)d_in[6];
  const float* reg5 = (const float*)d_in[7];
  const float* gt5  = (const float*)d_in[8];

  float* ws = (float*)d_ws;
  float* out = (float*)d_out;
  unsigned* hist = (unsigned*)(ws + HIST_OFF);

  hipMemsetAsync(d_out, 0, 3 * sizeof(float), stream);
  // zero acc + sumgt + ccnt + state + hist in one shot
  hipMemsetAsync(ws + ACC_OFF, 0, (size_t)(CBUF_OFF - ACC_OFF) * sizeof(float), stream);

  pixel_kernel<<<dim3((80000 + 255) / 256, 2), 256, 0, stream>>>(cls3, reg3, gt3, ws + 0,      ws + PART_OFF + 0 * PART_STRIDE, hist + 0 * 65536, 80000, 10000);
  pixel_kernel<<<dim3((20000 + 255) / 256, 2), 256, 0, stream>>>(cls4, reg4, gt4, ws + 80000,  ws + PART_OFF + 1 * PART_STRIDE, hist + 1 * 65536, 20000, 2500);
  pixel_kernel<<<dim3(( 5000 + 255) / 256, 2), 256, 0, stream>>>(cls5, reg5, gt5, ws + 100000, ws + PART_OFF + 2 * PART_STRIDE, hist + 2 * 65536,  5000, 625);

  select_bin_kernel<<<3, 256, 0, stream>>>(ws);
  compact_kernel<<<dim3(96, 3), 256, 0, stream>>>(ws);
  final_kernel<<<3, 256, 0, stream>>>(ws, out);
}